// Round 18
// baseline (1722.848 us; speedup 1.0000x reference)
//
#include <hip/hip_runtime.h>
#include <stdint.h>

#define HID 512
#define IND 256
#define OUTD 256
#define BROWS 32

typedef __attribute__((ext_vector_type(8))) short    short8;
typedef __attribute__((ext_vector_type(8))) _Float16 half8;   // 8 fp16 (4 VGPRs)
typedef __attribute__((ext_vector_type(4))) short    short4v;
typedef __attribute__((ext_vector_type(4))) float    f32x4;

#define MFMAH(a,b,c) __builtin_amdgcn_mfma_f32_16x16x32_f16(a,b,c,0,0,0)

__device__ __forceinline__ short f2h(float f){
  _Float16 h = (_Float16)f;
  return __builtin_bit_cast(short, h);
}
__device__ __forceinline__ float h2f(short s){
  return (float)__builtin_bit_cast(_Float16, s);
}
// Explicit accum-half parking for step-invariant xe (exact f32 bits).
__device__ __forceinline__ int to_agpr(int v){
  int a;
  asm("v_accvgpr_write_b32 %0, %1" : "=a"(a) : "v"(v));
  return a;
}
__device__ __forceinline__ int from_agpr(int a){
  int v;
  asm("v_accvgpr_read_b32 %0, %1" : "=v"(v) : "a"(a));
  return v;
}
__device__ __forceinline__ float tanh_fast(float x){
  float e = __builtin_amdgcn_exp2f(x * 2.88539008177792681472f);
  return __builtin_fmaf(-2.0f, __builtin_amdgcn_rcpf(e + 1.0f), 1.0f);
}
__device__ __forceinline__ float neigh(float v){
  return __builtin_bit_cast(float,
      __builtin_amdgcn_mov_dpp(__builtin_bit_cast(int, v), 0xB1, 0xF, 0xF, true));
}
__device__ __forceinline__ uint32_t axor(uint32_t b){ return b ^ (((b>>7)&7u)<<4); }

// ---------------- sigma ----------------
__global__ void sigma_kernel(const float* __restrict__ lw, const float* __restrict__ lu,
                             const float* __restrict__ ow, const float* __restrict__ ou,
                             float* __restrict__ invs)
{
  __shared__ float sv[HID];
  __shared__ float red[8];
  const int g = threadIdx.x;
  const int m = blockIdx.x;
  const float* W = (m < 3) ? (lw + (size_t)m*HID*HID) : ow;
  const float* u = (m < 3) ? (lu + m*HID) : ou;
  float t1 = 0.f;
  for (int k = 0; k < HID; ++k) t1 += W[(size_t)k*HID + g] * u[k];
  float ss = t1*t1;
  #pragma unroll
  for (int d = 32; d; d >>= 1) ss += __shfl_xor(ss, d);
  if ((g & 63) == 0) red[g >> 6] = ss;
  __syncthreads();
  float tot = 0.f;
  #pragma unroll
  for (int i = 0; i < 8; ++i) tot += red[i];
  float nrm = sqrtf(tot);
  sv[g] = t1 / (nrm + 1e-12f);
  __syncthreads();
  float n = 0.f;
  const float* Wr = W + (size_t)g*HID;
  for (int k = 0; k < HID; ++k) n += Wr[k] * sv[k];
  float ss2 = n*n;
  #pragma unroll
  for (int d = 32; d; d >>= 1) ss2 += __shfl_xor(ss2, d);
  if ((g & 63) == 0) red[g >> 6] = ss2;
  __syncthreads();
  float tot2 = 0.f;
  #pragma unroll
  for (int i = 0; i < 8; ++i) tot2 += red[i];
  float nn = sqrtf(tot2);
  float sigma = tot2 / (nn + 1e-12f);
  if (g == 0) invs[m] = 1.0f / sigma;
}

// ---------------- weight packing: SINGLE fp16, frag-sequential 1 KiB frags ----------------
__global__ void pack_wsum_f16(const float* __restrict__ lw, const float* __restrict__ invs,
                              short* __restrict__ pw)
{
  int i = blockIdx.x*blockDim.x + threadIdx.x;   // < 512*512
  int j = i & 7, lane = (i >> 3) & 63, f = i >> 9;
  int kt = f >> 5, ctg = f & 31;                 // NCT = 32
  int k = kt*32 + (lane >> 4)*8 + j;
  int g = ctg*16 + (lane & 15);
  size_t idx = (size_t)g*HID + k;
  float v = lw[idx]*invs[0] + lw[262144 + idx]*invs[1] + lw[524288 + idx]*invs[2];
  pw[i] = f2h(v);
}

template<int K, int N>
__global__ void pack_b_f16(const float* __restrict__ W, short* __restrict__ pb)
{
  int i = blockIdx.x*blockDim.x + threadIdx.x;   // < K*N
  int j = i & 7, lane = (i >> 3) & 63, f = i >> 9;
  constexpr int NCT = N/16;
  int kt = f / NCT, ctg = f % NCT;
  int k = kt*32 + (lane >> 4)*8 + j;
  int c = ctg*16 + (lane & 15);
  pb[i] = f2h(W[(size_t)c*K + k]);
}

__global__ void pack_small(const float* __restrict__ lb, const float* __restrict__ ow,
                           const float* __restrict__ invs,
                           float* __restrict__ bsum, float* __restrict__ cs, float* __restrict__ cn)
{
  int g = blockIdx.x*blockDim.x + threadIdx.x;
  if (g >= HID) return;
  bsum[g] = lb[g] + lb[HID + g] + lb[2*HID + g];
  float is = invs[3];
  cs[g] = ow[(size_t)g*HID + g] * is;
  cn[g] = ow[(size_t)g*HID + (g^1)] * is;
}

// ---------------- fused main: 32 rows, 512 threads (8 waves), wave tile 32x64 ----------------
// R14 base (best known: 1578 us, zero spill) + two minimal changes:
//  (1) depth-1 cross-step W prefetch with FIXED addresses: kt=0,1 B-frags
//      (pa/qa) consumed at loop top, refilled immediately from baseW/baseW+32K
//      for the NEXT step — no conditionals (R17's cndmask chains regressed).
//  (2) double-buffered A_hi tile -> ONE barrier per step.
// Regs: arch ~ h32 + pa/qa32 + transients ~= 100-110 <= 128; accum acc32+xe32=64.
__global__ void __launch_bounds__(512) fused_main(
    const float* __restrict__ x,
    const float* __restrict__ winb,
    const float* __restrict__ headb,
    const int*  __restrict__ stepsp,
    const short* __restrict__ packW,    // Wsum fp16, 512 KiB
    const short* __restrict__ packI,    // W_in fp16, 256 KiB
    const short* __restrict__ packHd,   // head fp16, 256 KiB
    const float* __restrict__ bsumA,
    const float* __restrict__ csA,
    const float* __restrict__ cnA,
    float* __restrict__ out)
{
  __shared__ char ldsbuf[98304];
  char* ldsA0 = ldsbuf;             // 32 KiB A_hi buffer 0 (frag-major, 32 x 1 KiB)
  char* ldsA1 = ldsbuf + 32768;     // 32 KiB A_hi buffer 1
  char* ldsLo = ldsbuf + 65536;     // 32 KiB A_lo (x_emb + head phases only)
  const int tid  = threadIdx.x;
  const int lane = tid & 63;
  const int l15  = lane & 15;
  const int ql   = lane >> 4;
  const int wc   = tid >> 6;        // 0..7, col group of 64
  const int rb   = blockIdx.x;

  const uint32_t laneRd = (uint32_t)((lane*16) ^ (((lane>>3)&7)<<4));

  // ---- stage x tile -> LDS fp16 hi/lo, frag-major [rg 0..1][kt 0..7] ----
  {
    const float* xb = x + (size_t)rb*BROWS*IND;
    #pragma unroll
    for (int i = 0; i < 4; ++i) {
      int fi  = i*512 + tid;        // 2048 float4s
      int row = fi >> 6;
      int c   = (fi & 63)*4;
      f32x4 v = *(const f32x4*)(xb + (size_t)row*IND + c);
      short4v hi4, lo4;
      #pragma unroll
      for (int j = 0; j < 4; ++j) {
        short hh = f2h(v[j]);
        hi4[j] = hh;
        lo4[j] = f2h(v[j] - h2f(hh));
      }
      int rg = row >> 4, kt = c >> 5, qd = (c >> 3) & 3;
      uint32_t byte = (uint32_t)(((rg*8 + kt)*1024) + (qd*16 + (row & 15))*16 + (c & 7)*2);
      *(short4v*)(ldsA0 + axor(byte)) = hi4;
      *(short4v*)(ldsLo + axor(byte)) = lo4;
    }
  }
  __syncthreads();

  const int nsteps = stepsp[0];

  const float cs_s = csA[wc*64 + l15];
  const float cn_s = cnA[wc*64 + l15];

  // ---- x_emb: ct-halves (accum peak 16+32), fp16 2-pass (exact A) ----
  f32x4 h[2][4];
  int xpa[2][4][4];   // exact f32 bits of xe, explicit AGPR, static indexing
  #pragma unroll
  for (int ch = 0; ch < 2; ++ch) {
    f32x4 acc[2][2];
    #pragma unroll
    for (int c2 = 0; c2 < 2; ++c2) {
      int c = wc*64 + (ch*2 + c2)*16 + l15;
      float s = winb[c] + bsumA[c];
      #pragma unroll
      for (int rt = 0; rt < 2; ++rt) {
        f32x4 z; z[0]=s; z[1]=s; z[2]=s; z[3]=s;
        acc[rt][c2] = z;
      }
    }
    {
      const char* pI = (const char*)packI + (size_t)wc*4096 + (size_t)(ch*2048) + (size_t)lane*16;
      __builtin_amdgcn_s_setprio(1);
      #pragma unroll 2
      for (int kt = 0; kt < 8; ++kt) {
        half8 b0 = *(const half8*)(pI);
        half8 b1 = *(const half8*)(pI + 1024);
        #pragma unroll
        for (int rt = 0; rt < 2; ++rt) {
          half8 ah = *(const half8*)(ldsA0 + laneRd + (rt*8 + kt)*1024);
          half8 al = *(const half8*)(ldsLo + laneRd + (rt*8 + kt)*1024);
          acc[rt][0] = MFMAH(ah, b0, acc[rt][0]);
          acc[rt][0] = MFMAH(al, b0, acc[rt][0]);
          acc[rt][1] = MFMAH(ah, b1, acc[rt][1]);
          acc[rt][1] = MFMAH(al, b1, acc[rt][1]);
        }
        pI += 32768;
      }
      __builtin_amdgcn_s_setprio(0);
    }
    #pragma unroll
    for (int rt = 0; rt < 2; ++rt)
      #pragma unroll
      for (int c2 = 0; c2 < 2; ++c2) {
        int ct = ch*2 + c2;
        #pragma unroll
        for (int r = 0; r < 4; ++r) {
          float xv = acc[rt][c2][r];
          xpa[rt][ct][r] = to_agpr(__builtin_bit_cast(int, xv));
          h[rt][ct][r] = (nsteps >= 1) ? 0.5f * tanh_fast(xv) : 0.f;
        }
      }
  }
  __syncthreads();   // x-tile reads done before s=0 overwrites A0

  const char* baseW = (const char*)packW + (size_t)wc*4096 + (size_t)lane*16;

  // depth-1 cross-step prefetch: kt=0 (pa*), kt=1 (qa*) — fixed addresses
  half8 pa0 = *(const half8*)(baseW);
  half8 pa1 = *(const half8*)(baseW + 1024);
  half8 pa2 = *(const half8*)(baseW + 2048);
  half8 pa3 = *(const half8*)(baseW + 3072);
  half8 qa0 = *(const half8*)(baseW + 32768);
  half8 qa1 = *(const half8*)(baseW + 32768 + 1024);
  half8 qa2 = *(const half8*)(baseW + 32768 + 2048);
  half8 qa3 = *(const half8*)(baseW + 32768 + 3072);

  // write-address components (loop-invariant)
  uint32_t wcomp[4];
  #pragma unroll
  for (int ct = 0; ct < 4; ++ct) {
    int c = wc*64 + ct*16 + l15;
    wcomp[ct] = (uint32_t)(((c >> 5)*1024) + (((c >> 3) & 3)*256) + ((c & 7)*2) + ql*64);
  }

  // ---- recurrence: nsteps-1 iterations, ONE barrier each ----
  for (int s = 0; s < nsteps - 1; ++s) {
    char* wrHi = (s & 1) ? ldsA1 : ldsA0;
    // t = tanh(h) -> A[s&1] hi-plane
    #pragma unroll
    for (int rt = 0; rt < 2; ++rt) {
      uint32_t rcomp = (uint32_t)(rt*16384);
      #pragma unroll
      for (int ct = 0; ct < 4; ++ct)
        #pragma unroll
        for (int r = 0; r < 4; ++r) {
          float t = tanh_fast(h[rt][ct][r]);
          *(short*)(wrHi + axor(rcomp + wcomp[ct] + (uint32_t)(r*16))) = f2h(t);
        }
    }
    __syncthreads();

    f32x4 acc[2][4];
    #pragma unroll
    for (int rt = 0; rt < 2; ++rt)
      #pragma unroll
      for (int ct = 0; ct < 4; ++ct)
        #pragma unroll
        for (int r = 0; r < 4; ++r) {
          float hv = h[rt][ct][r];
          float xe = __builtin_bit_cast(float, from_agpr(xpa[rt][ct][r]));
          acc[rt][ct][r] = __builtin_fmaf(cs_s, hv,
                             __builtin_fmaf(cn_s, neigh(hv), xe));
        }
    {
      const char* rdHi = wrHi;
      __builtin_amdgcn_s_setprio(1);
      // kt=0: consume pa*, refill immediately for next step (fixed addr)
      {
        half8 b0 = pa0, b1 = pa1, b2 = pa2, b3 = pa3;
        pa0 = *(const half8*)(baseW);
        pa1 = *(const half8*)(baseW + 1024);
        pa2 = *(const half8*)(baseW + 2048);
        pa3 = *(const half8*)(baseW + 3072);
        half8 ah0 = *(const half8*)(rdHi + laneRd + (0*16 + 0)*1024);
        half8 ah1 = *(const half8*)(rdHi + laneRd + (1*16 + 0)*1024);
        acc[0][0] = MFMAH(ah0, b0, acc[0][0]);
        acc[1][0] = MFMAH(ah1, b0, acc[1][0]);
        acc[0][1] = MFMAH(ah0, b1, acc[0][1]);
        acc[1][1] = MFMAH(ah1, b1, acc[1][1]);
        acc[0][2] = MFMAH(ah0, b2, acc[0][2]);
        acc[1][2] = MFMAH(ah1, b2, acc[1][2]);
        acc[0][3] = MFMAH(ah0, b3, acc[0][3]);
        acc[1][3] = MFMAH(ah1, b3, acc[1][3]);
      }
      // kt=1: consume qa*, refill immediately (fixed addr)
      {
        half8 b0 = qa0, b1 = qa1, b2 = qa2, b3 = qa3;
        qa0 = *(const half8*)(baseW + 32768);
        qa1 = *(const half8*)(baseW + 32768 + 1024);
        qa2 = *(const half8*)(baseW + 32768 + 2048);
        qa3 = *(const half8*)(baseW + 32768 + 3072);
        half8 ah0 = *(const half8*)(rdHi + laneRd + (0*16 + 1)*1024);
        half8 ah1 = *(const half8*)(rdHi + laneRd + (1*16 + 1)*1024);
        acc[0][0] = MFMAH(ah0, b0, acc[0][0]);
        acc[1][0] = MFMAH(ah1, b0, acc[1][0]);
        acc[0][1] = MFMAH(ah0, b1, acc[0][1]);
        acc[1][1] = MFMAH(ah1, b1, acc[1][1]);
        acc[0][2] = MFMAH(ah0, b2, acc[0][2]);
        acc[1][2] = MFMAH(ah1, b2, acc[1][2]);
        acc[0][3] = MFMAH(ah0, b3, acc[0][3]);
        acc[1][3] = MFMAH(ah1, b3, acc[1][3]);
      }
      // kt = 2..15
      const char* p = baseW + 65536;
      #pragma unroll 2
      for (int kt = 2; kt < 16; ++kt) {
        half8 b0 = *(const half8*)(p);
        half8 b1 = *(const half8*)(p + 1024);
        half8 b2 = *(const half8*)(p + 2048);
        half8 b3 = *(const half8*)(p + 3072);
        half8 ah0 = *(const half8*)(rdHi + laneRd + (0*16 + kt)*1024);
        half8 ah1 = *(const half8*)(rdHi + laneRd + (1*16 + kt)*1024);
        acc[0][0] = MFMAH(ah0, b0, acc[0][0]);
        acc[1][0] = MFMAH(ah1, b0, acc[1][0]);
        acc[0][1] = MFMAH(ah0, b1, acc[0][1]);
        acc[1][1] = MFMAH(ah1, b1, acc[1][1]);
        acc[0][2] = MFMAH(ah0, b2, acc[0][2]);
        acc[1][2] = MFMAH(ah1, b2, acc[1][2]);
        acc[0][3] = MFMAH(ah0, b3, acc[0][3]);
        acc[1][3] = MFMAH(ah1, b3, acc[1][3]);
        p += 32768;
      }
      __builtin_amdgcn_s_setprio(0);
    }
    // h update
    #pragma unroll
    for (int rt = 0; rt < 2; ++rt)
      #pragma unroll
      for (int ct = 0; ct < 4; ++ct)
        #pragma unroll
        for (int r = 0; r < 4; ++r)
          h[rt][ct][r] = __builtin_fmaf(0.5f, tanh_fast(acc[rt][ct][r]), 0.5f*h[rt][ct][r]);
    // no trailing barrier: next step writes the OTHER A buffer
  }
  __syncthreads();   // all waves done with A buffers before head stores

  // ---- head: out = h @ head_w^T + head_b (h split hi/lo fp16, W single fp16) ----
  #pragma unroll
  for (int rt = 0; rt < 2; ++rt) {
    uint32_t rcomp = (uint32_t)(rt*16384);
    #pragma unroll
    for (int ct = 0; ct < 4; ++ct)
      #pragma unroll
      for (int r = 0; r < 4; ++r) {
        float hv = h[rt][ct][r];
        short hh = f2h(hv);
        uint32_t byte = axor(rcomp + wcomp[ct] + (uint32_t)(r*16));
        *(short*)(ldsA0 + byte) = hh;
        *(short*)(ldsLo + byte) = f2h(hv - h2f(hh));
      }
  }
  __syncthreads();

  int oc[2]; float hbv[2];
  #pragma unroll
  for (int c2 = 0; c2 < 2; ++c2) { oc[c2] = wc*32 + c2*16 + l15; hbv[c2] = headb[oc[c2]]; }
  f32x4 o[2][2];
  #pragma unroll
  for (int rt = 0; rt < 2; ++rt)
    #pragma unroll
    for (int c2 = 0; c2 < 2; ++c2) {
      f32x4 z; z[0]=hbv[c2]; z[1]=hbv[c2]; z[2]=hbv[c2]; z[3]=hbv[c2];
      o[rt][c2] = z;
    }
  {
    const char* pHd = (const char*)packHd + (size_t)wc*2048 + (size_t)lane*16;
    #pragma unroll 2
    for (int kt = 0; kt < 16; ++kt) {
      #pragma unroll
      for (int rt = 0; rt < 2; ++rt) {
        half8 ah = *(const half8*)(ldsA0 + laneRd + (rt*16 + kt)*1024);
        half8 al = *(const half8*)(ldsLo + laneRd + (rt*16 + kt)*1024);
        #pragma unroll
        for (int c2 = 0; c2 < 2; ++c2) {
          half8 b = *(const half8*)(pHd + c2*1024);
          o[rt][c2] = MFMAH(ah, b, o[rt][c2]);
          o[rt][c2] = MFMAH(al, b, o[rt][c2]);
        }
      }
      pHd += 16384;
    }
  }
  const size_t rowg = (size_t)rb*BROWS;
  #pragma unroll
  for (int rt = 0; rt < 2; ++rt)
    #pragma unroll
    for (int c2 = 0; c2 < 2; ++c2)
      #pragma unroll
      for (int r = 0; r < 4; ++r) {
        size_t row = rowg + rt*16 + ql*4 + r;
        out[row*OUTD + oc[c2]] = o[rt][c2][r];
      }
}

extern "C" void kernel_launch(void* const* d_in, const int* in_sizes, int n_in,
                              void* d_out, int out_size, void* d_ws, size_t ws_size,
                              hipStream_t stream)
{
  const float* x    = (const float*)d_in[0];
  const float* winw = (const float*)d_in[1];
  const float* winb = (const float*)d_in[2];
  const float* lw   = (const float*)d_in[3];
  const float* lb   = (const float*)d_in[4];
  const float* lu   = (const float*)d_in[5];
  const float* ow   = (const float*)d_in[6];
  const float* ou   = (const float*)d_in[7];
  const float* hw   = (const float*)d_in[8];
  const float* hb   = (const float*)d_in[9];
  const int*   st   = (const int*)d_in[10];
  float* out = (float*)d_out;
  char*  ws  = (char*)d_ws;

  float* invs   = (float*)(ws);
  float* bsum   = (float*)(ws + 1024);
  float* cs     = (float*)(ws + 4096);
  float* cn     = (float*)(ws + 8192);
  short* packW  = (short*)(ws + 16384);                    // 512 KiB fp16
  short* packI  = (short*)(ws + 16384 + 524288);           // 256 KiB fp16
  short* packHd = (short*)(ws + 16384 + 524288 + 262144);  // 256 KiB fp16

  sigma_kernel<<<4, 512, 0, stream>>>(lw, lu, ow, ou, invs);
  pack_wsum_f16<<<1024, 256, 0, stream>>>(lw, invs, packW);
  pack_b_f16<256, 512><<<512, 256, 0, stream>>>(winw, packI);
  pack_b_f16<512, 256><<<512, 256, 0, stream>>>(hw, packHd);
  pack_small<<<2, 256, 0, stream>>>(lb, ow, invs, bsum, cs, cn);

  fused_main<<<65536/BROWS, 512, 0, stream>>>(x, winb, hb, st,
                                              packW, packI, packHd,
                                              bsum, cs, cn, out);
}

// Round 19
// 1720.168 us; speedup vs baseline: 1.0016x; 1.0016x over previous
//
#include <hip/hip_runtime.h>
#include <stdint.h>

#define HID 512
#define IND 256
#define OUTD 256
#define BROWS 32

typedef __attribute__((ext_vector_type(8))) short    short8;
typedef __attribute__((ext_vector_type(8))) _Float16 half8;   // 8 fp16 (4 VGPRs)
typedef __attribute__((ext_vector_type(4))) short    short4v;
typedef __attribute__((ext_vector_type(4))) float    f32x4;

#define MFMAH(a,b,c) __builtin_amdgcn_mfma_f32_16x16x32_f16(a,b,c,0,0,0)

__device__ __forceinline__ short f2h(float f){
  _Float16 h = (_Float16)f;
  return __builtin_bit_cast(short, h);
}
__device__ __forceinline__ float h2f(short s){
  return (float)__builtin_bit_cast(_Float16, s);
}
// Explicit accum-half parking for step-invariant xe (exact f32 bits).
__device__ __forceinline__ int to_agpr(int v){
  int a;
  asm("v_accvgpr_write_b32 %0, %1" : "=a"(a) : "v"(v));
  return a;
}
__device__ __forceinline__ int from_agpr(int a){
  int v;
  asm("v_accvgpr_read_b32 %0, %1" : "=v"(v) : "a"(a));
  return v;
}
__device__ __forceinline__ float tanh_fast(float x){
  float e = __builtin_amdgcn_exp2f(x * 2.88539008177792681472f);
  return __builtin_fmaf(-2.0f, __builtin_amdgcn_rcpf(e + 1.0f), 1.0f);
}
__device__ __forceinline__ float neigh(float v){
  return __builtin_bit_cast(float,
      __builtin_amdgcn_mov_dpp(__builtin_bit_cast(int, v), 0xB1, 0xF, 0xF, true));
}
__device__ __forceinline__ uint32_t axor(uint32_t b){ return b ^ (((b>>7)&7u)<<4); }

// ---------------- sigma ----------------
__global__ void sigma_kernel(const float* __restrict__ lw, const float* __restrict__ lu,
                             const float* __restrict__ ow, const float* __restrict__ ou,
                             float* __restrict__ invs)
{
  __shared__ float sv[HID];
  __shared__ float red[8];
  const int g = threadIdx.x;
  const int m = blockIdx.x;
  const float* W = (m < 3) ? (lw + (size_t)m*HID*HID) : ow;
  const float* u = (m < 3) ? (lu + m*HID) : ou;
  float t1 = 0.f;
  for (int k = 0; k < HID; ++k) t1 += W[(size_t)k*HID + g] * u[k];
  float ss = t1*t1;
  #pragma unroll
  for (int d = 32; d; d >>= 1) ss += __shfl_xor(ss, d);
  if ((g & 63) == 0) red[g >> 6] = ss;
  __syncthreads();
  float tot = 0.f;
  #pragma unroll
  for (int i = 0; i < 8; ++i) tot += red[i];
  float nrm = sqrtf(tot);
  sv[g] = t1 / (nrm + 1e-12f);
  __syncthreads();
  float n = 0.f;
  const float* Wr = W + (size_t)g*HID;
  for (int k = 0; k < HID; ++k) n += Wr[k] * sv[k];
  float ss2 = n*n;
  #pragma unroll
  for (int d = 32; d; d >>= 1) ss2 += __shfl_xor(ss2, d);
  if ((g & 63) == 0) red[g >> 6] = ss2;
  __syncthreads();
  float tot2 = 0.f;
  #pragma unroll
  for (int i = 0; i < 8; ++i) tot2 += red[i];
  float nn = sqrtf(tot2);
  float sigma = tot2 / (nn + 1e-12f);
  if (g == 0) invs[m] = 1.0f / sigma;
}

// ---------------- weight packing: SINGLE fp16, frag-sequential 1 KiB frags ----------------
__global__ void pack_wsum_f16(const float* __restrict__ lw, const float* __restrict__ invs,
                              short* __restrict__ pw)
{
  int i = blockIdx.x*blockDim.x + threadIdx.x;   // < 512*512
  int j = i & 7, lane = (i >> 3) & 63, f = i >> 9;
  int kt = f >> 5, ctg = f & 31;                 // NCT = 32
  int k = kt*32 + (lane >> 4)*8 + j;
  int g = ctg*16 + (lane & 15);
  size_t idx = (size_t)g*HID + k;
  float v = lw[idx]*invs[0] + lw[262144 + idx]*invs[1] + lw[524288 + idx]*invs[2];
  pw[i] = f2h(v);
}

template<int K, int N>
__global__ void pack_b_f16(const float* __restrict__ W, short* __restrict__ pb)
{
  int i = blockIdx.x*blockDim.x + threadIdx.x;   // < K*N
  int j = i & 7, lane = (i >> 3) & 63, f = i >> 9;
  constexpr int NCT = N/16;
  int kt = f / NCT, ctg = f % NCT;
  int k = kt*32 + (lane >> 4)*8 + j;
  int c = ctg*16 + (lane & 15);
  pb[i] = f2h(W[(size_t)c*K + k]);
}

__global__ void pack_small(const float* __restrict__ lb, const float* __restrict__ ow,
                           const float* __restrict__ invs,
                           float* __restrict__ bsum, float* __restrict__ cs, float* __restrict__ cn)
{
  int g = blockIdx.x*blockDim.x + threadIdx.x;
  if (g >= HID) return;
  bsum[g] = lb[g] + lb[HID + g] + lb[2*HID + g];
  float is = invs[3];
  cs[g] = ow[(size_t)g*HID + g] * is;
  cn[g] = ow[(size_t)g*HID + (g^1)] * is;
}

// ---------------- fused main: 32 rows, 512 threads (8 waves), wave tile 32x64 ----------------
// R14 base (best known: 1578 us) + ONE isolated change: double-buffered A_hi
// tile -> one barrier per step (no W-prefetch registers — R17/R18 showed the
// held pa/qa regs starve load-scheduling slack and regress).
// Regs: arch ~ h32 + transients ~= 92-96; accum acc32+xe32=64. LDS 96 KiB.
__global__ void __launch_bounds__(512) fused_main(
    const float* __restrict__ x,
    const float* __restrict__ winb,
    const float* __restrict__ headb,
    const int*  __restrict__ stepsp,
    const short* __restrict__ packW,    // Wsum fp16, 512 KiB
    const short* __restrict__ packI,    // W_in fp16, 256 KiB
    const short* __restrict__ packHd,   // head fp16, 256 KiB
    const float* __restrict__ bsumA,
    const float* __restrict__ csA,
    const float* __restrict__ cnA,
    float* __restrict__ out)
{
  __shared__ char ldsbuf[98304];
  char* ldsA0 = ldsbuf;             // 32 KiB A_hi buffer 0 (frag-major, 32 x 1 KiB)
  char* ldsA1 = ldsbuf + 32768;     // 32 KiB A_hi buffer 1
  char* ldsLo = ldsbuf + 65536;     // 32 KiB A_lo (x_emb + head phases only)
  const int tid  = threadIdx.x;
  const int lane = tid & 63;
  const int l15  = lane & 15;
  const int ql   = lane >> 4;
  const int wc   = tid >> 6;        // 0..7, col group of 64
  const int rb   = blockIdx.x;

  const uint32_t laneRd = (uint32_t)((lane*16) ^ (((lane>>3)&7)<<4));

  // ---- stage x tile -> LDS fp16 hi/lo, frag-major [rg 0..1][kt 0..7] ----
  {
    const float* xb = x + (size_t)rb*BROWS*IND;
    #pragma unroll
    for (int i = 0; i < 4; ++i) {
      int fi  = i*512 + tid;        // 2048 float4s
      int row = fi >> 6;
      int c   = (fi & 63)*4;
      f32x4 v = *(const f32x4*)(xb + (size_t)row*IND + c);
      short4v hi4, lo4;
      #pragma unroll
      for (int j = 0; j < 4; ++j) {
        short hh = f2h(v[j]);
        hi4[j] = hh;
        lo4[j] = f2h(v[j] - h2f(hh));
      }
      int rg = row >> 4, kt = c >> 5, qd = (c >> 3) & 3;
      uint32_t byte = (uint32_t)(((rg*8 + kt)*1024) + (qd*16 + (row & 15))*16 + (c & 7)*2);
      *(short4v*)(ldsA0 + axor(byte)) = hi4;
      *(short4v*)(ldsLo + axor(byte)) = lo4;
    }
  }
  __syncthreads();

  const int nsteps = stepsp[0];

  const float cs_s = csA[wc*64 + l15];
  const float cn_s = cnA[wc*64 + l15];

  // ---- x_emb: ct-halves (accum peak 16+32), fp16 2-pass (exact A) ----
  f32x4 h[2][4];
  int xpa[2][4][4];   // exact f32 bits of xe, explicit AGPR, static indexing
  #pragma unroll
  for (int ch = 0; ch < 2; ++ch) {
    f32x4 acc[2][2];
    #pragma unroll
    for (int c2 = 0; c2 < 2; ++c2) {
      int c = wc*64 + (ch*2 + c2)*16 + l15;
      float s = winb[c] + bsumA[c];
      #pragma unroll
      for (int rt = 0; rt < 2; ++rt) {
        f32x4 z; z[0]=s; z[1]=s; z[2]=s; z[3]=s;
        acc[rt][c2] = z;
      }
    }
    {
      const char* pI = (const char*)packI + (size_t)wc*4096 + (size_t)(ch*2048) + (size_t)lane*16;
      __builtin_amdgcn_s_setprio(1);
      #pragma unroll 2
      for (int kt = 0; kt < 8; ++kt) {
        half8 b0 = *(const half8*)(pI);
        half8 b1 = *(const half8*)(pI + 1024);
        #pragma unroll
        for (int rt = 0; rt < 2; ++rt) {
          half8 ah = *(const half8*)(ldsA0 + laneRd + (rt*8 + kt)*1024);
          half8 al = *(const half8*)(ldsLo + laneRd + (rt*8 + kt)*1024);
          acc[rt][0] = MFMAH(ah, b0, acc[rt][0]);
          acc[rt][0] = MFMAH(al, b0, acc[rt][0]);
          acc[rt][1] = MFMAH(ah, b1, acc[rt][1]);
          acc[rt][1] = MFMAH(al, b1, acc[rt][1]);
        }
        pI += 32768;
      }
      __builtin_amdgcn_s_setprio(0);
    }
    #pragma unroll
    for (int rt = 0; rt < 2; ++rt)
      #pragma unroll
      for (int c2 = 0; c2 < 2; ++c2) {
        int ct = ch*2 + c2;
        #pragma unroll
        for (int r = 0; r < 4; ++r) {
          float xv = acc[rt][c2][r];
          xpa[rt][ct][r] = to_agpr(__builtin_bit_cast(int, xv));
          h[rt][ct][r] = (nsteps >= 1) ? 0.5f * tanh_fast(xv) : 0.f;
        }
      }
  }
  __syncthreads();   // x-tile reads done before s=0 overwrites A0

  const char* baseW = (const char*)packW + (size_t)wc*4096 + (size_t)lane*16;

  // write-address components (loop-invariant)
  uint32_t wcomp[4];
  #pragma unroll
  for (int ct = 0; ct < 4; ++ct) {
    int c = wc*64 + ct*16 + l15;
    wcomp[ct] = (uint32_t)(((c >> 5)*1024) + (((c >> 3) & 3)*256) + ((c & 7)*2) + ql*64);
  }

  // ---- recurrence: nsteps-1 iterations, ONE barrier each ----
  for (int s = 0; s < nsteps - 1; ++s) {
    char* wrHi = (s & 1) ? ldsA1 : ldsA0;
    // t = tanh(h) -> A[s&1] hi-plane
    #pragma unroll
    for (int rt = 0; rt < 2; ++rt) {
      uint32_t rcomp = (uint32_t)(rt*16384);
      #pragma unroll
      for (int ct = 0; ct < 4; ++ct)
        #pragma unroll
        for (int r = 0; r < 4; ++r) {
          float t = tanh_fast(h[rt][ct][r]);
          *(short*)(wrHi + axor(rcomp + wcomp[ct] + (uint32_t)(r*16))) = f2h(t);
        }
    }
    __syncthreads();

    f32x4 acc[2][4];
    #pragma unroll
    for (int rt = 0; rt < 2; ++rt)
      #pragma unroll
      for (int ct = 0; ct < 4; ++ct)
        #pragma unroll
        for (int r = 0; r < 4; ++r) {
          float hv = h[rt][ct][r];
          float xe = __builtin_bit_cast(float, from_agpr(xpa[rt][ct][r]));
          acc[rt][ct][r] = __builtin_fmaf(cs_s, hv,
                             __builtin_fmaf(cn_s, neigh(hv), xe));
        }
    {
      const char* rdHi = wrHi;
      const char* p = baseW;
      __builtin_amdgcn_s_setprio(1);
      #pragma unroll 2
      for (int kt = 0; kt < 16; ++kt) {
        half8 b0 = *(const half8*)(p);
        half8 b1 = *(const half8*)(p + 1024);
        half8 b2 = *(const half8*)(p + 2048);
        half8 b3 = *(const half8*)(p + 3072);
        half8 ah0 = *(const half8*)(rdHi + laneRd + (0*16 + kt)*1024);
        half8 ah1 = *(const half8*)(rdHi + laneRd + (1*16 + kt)*1024);
        acc[0][0] = MFMAH(ah0, b0, acc[0][0]);
        acc[1][0] = MFMAH(ah1, b0, acc[1][0]);
        acc[0][1] = MFMAH(ah0, b1, acc[0][1]);
        acc[1][1] = MFMAH(ah1, b1, acc[1][1]);
        acc[0][2] = MFMAH(ah0, b2, acc[0][2]);
        acc[1][2] = MFMAH(ah1, b2, acc[1][2]);
        acc[0][3] = MFMAH(ah0, b3, acc[0][3]);
        acc[1][3] = MFMAH(ah1, b3, acc[1][3]);
        p += 32768;
      }
      __builtin_amdgcn_s_setprio(0);
    }
    // h update
    #pragma unroll
    for (int rt = 0; rt < 2; ++rt)
      #pragma unroll
      for (int ct = 0; ct < 4; ++ct)
        #pragma unroll
        for (int r = 0; r < 4; ++r)
          h[rt][ct][r] = __builtin_fmaf(0.5f, tanh_fast(acc[rt][ct][r]), 0.5f*h[rt][ct][r]);
    // no trailing barrier: next step writes the OTHER A buffer
  }
  __syncthreads();   // all waves done with A buffers before head stores

  // ---- head: out = h @ head_w^T + head_b (h split hi/lo fp16, W single fp16) ----
  #pragma unroll
  for (int rt = 0; rt < 2; ++rt) {
    uint32_t rcomp = (uint32_t)(rt*16384);
    #pragma unroll
    for (int ct = 0; ct < 4; ++ct)
      #pragma unroll
      for (int r = 0; r < 4; ++r) {
        float hv = h[rt][ct][r];
        short hh = f2h(hv);
        uint32_t byte = axor(rcomp + wcomp[ct] + (uint32_t)(r*16));
        *(short*)(ldsA0 + byte) = hh;
        *(short*)(ldsLo + byte) = f2h(hv - h2f(hh));
      }
  }
  __syncthreads();

  int oc[2]; float hbv[2];
  #pragma unroll
  for (int c2 = 0; c2 < 2; ++c2) { oc[c2] = wc*32 + c2*16 + l15; hbv[c2] = headb[oc[c2]]; }
  f32x4 o[2][2];
  #pragma unroll
  for (int rt = 0; rt < 2; ++rt)
    #pragma unroll
    for (int c2 = 0; c2 < 2; ++c2) {
      f32x4 z; z[0]=hbv[c2]; z[1]=hbv[c2]; z[2]=hbv[c2]; z[3]=hbv[c2];
      o[rt][c2] = z;
    }
  {
    const char* pHd = (const char*)packHd + (size_t)wc*2048 + (size_t)lane*16;
    #pragma unroll 2
    for (int kt = 0; kt < 16; ++kt) {
      #pragma unroll
      for (int rt = 0; rt < 2; ++rt) {
        half8 ah = *(const half8*)(ldsA0 + laneRd + (rt*16 + kt)*1024);
        half8 al = *(const half8*)(ldsLo + laneRd + (rt*16 + kt)*1024);
        #pragma unroll
        for (int c2 = 0; c2 < 2; ++c2) {
          half8 b = *(const half8*)(pHd + c2*1024);
          o[rt][c2] = MFMAH(ah, b, o[rt][c2]);
          o[rt][c2] = MFMAH(al, b, o[rt][c2]);
        }
      }
      pHd += 16384;
    }
  }
  const size_t rowg = (size_t)rb*BROWS;
  #pragma unroll
  for (int rt = 0; rt < 2; ++rt)
    #pragma unroll
    for (int c2 = 0; c2 < 2; ++c2)
      #pragma unroll
      for (int r = 0; r < 4; ++r) {
        size_t row = rowg + rt*16 + ql*4 + r;
        out[row*OUTD + oc[c2]] = o[rt][c2][r];
      }
}

extern "C" void kernel_launch(void* const* d_in, const int* in_sizes, int n_in,
                              void* d_out, int out_size, void* d_ws, size_t ws_size,
                              hipStream_t stream)
{
  const float* x    = (const float*)d_in[0];
  const float* winw = (const float*)d_in[1];
  const float* winb = (const float*)d_in[2];
  const float* lw   = (const float*)d_in[3];
  const float* lb   = (const float*)d_in[4];
  const float* lu   = (const float*)d_in[5];
  const float* ow   = (const float*)d_in[6];
  const float* ou   = (const float*)d_in[7];
  const float* hw   = (const float*)d_in[8];
  const float* hb   = (const float*)d_in[9];
  const int*   st   = (const int*)d_in[10];
  float* out = (float*)d_out;
  char*  ws  = (char*)d_ws;

  float* invs   = (float*)(ws);
  float* bsum   = (float*)(ws + 1024);
  float* cs     = (float*)(ws + 4096);
  float* cn     = (float*)(ws + 8192);
  short* packW  = (short*)(ws + 16384);                    // 512 KiB fp16
  short* packI  = (short*)(ws + 16384 + 524288);           // 256 KiB fp16
  short* packHd = (short*)(ws + 16384 + 524288 + 262144);  // 256 KiB fp16

  sigma_kernel<<<4, 512, 0, stream>>>(lw, lu, ow, ou, invs);
  pack_wsum_f16<<<1024, 256, 0, stream>>>(lw, invs, packW);
  pack_b_f16<256, 512><<<512, 256, 0, stream>>>(winw, packI);
  pack_b_f16<512, 256><<<512, 256, 0, stream>>>(hw, packHd);
  pack_small<<<2, 256, 0, stream>>>(lb, ow, invs, bsum, cs, cn);

  fused_main<<<65536/BROWS, 512, 0, stream>>>(x, winb, hb, st,
                                              packW, packI, packHd,
                                              bsum, cs, cn, out);
}

// Round 20
// 1575.390 us; speedup vs baseline: 1.0936x; 1.0919x over previous
//
#include <hip/hip_runtime.h>
#include <stdint.h>

#define HID 512
#define IND 256
#define OUTD 256
#define BROWS 32

typedef __attribute__((ext_vector_type(8))) short    short8;
typedef __attribute__((ext_vector_type(8))) _Float16 half8;   // 8 fp16 (4 VGPRs)
typedef __attribute__((ext_vector_type(4))) short    short4v;
typedef __attribute__((ext_vector_type(4))) float    f32x4;
typedef __attribute__((ext_vector_type(4))) int      i32x4;

#define MFMAH(a,b,c) __builtin_amdgcn_mfma_f32_16x16x32_f16(a,b,c,0,0,0)

__device__ __forceinline__ short f2bf(float f){
  uint32_t u = __builtin_bit_cast(uint32_t, f);
  u += 0x7FFFu + ((u>>16)&1u);
  return (short)(u>>16);
}
__device__ __forceinline__ float bf2f(short s){
  uint32_t u = ((uint32_t)(uint16_t)s) << 16;
  return __builtin_bit_cast(float, u);
}
__device__ __forceinline__ short f2h(float f){
  _Float16 h = (_Float16)f;
  return __builtin_bit_cast(short, h);
}
__device__ __forceinline__ float h2f(short s){
  return (float)__builtin_bit_cast(_Float16, s);
}
// xe packed as (hi bf16 | lo bf16) in one u32 — 2^-16 rel precision
__device__ __forceinline__ int pack_hl(float v){
  short hi = f2bf(v);
  short lo = f2bf(v - bf2f(hi));
  return (((int)(uint16_t)hi) << 16) | (int)(uint16_t)lo;
}
__device__ __forceinline__ float unpk(int p){
  float vh = __builtin_bit_cast(float, (uint32_t)p & 0xFFFF0000u);
  float vl = __builtin_bit_cast(float, (uint32_t)p << 16);
  return vh + vl;
}
__device__ __forceinline__ float tanh_fast(float x){
  float e = __builtin_amdgcn_exp2f(x * 2.88539008177792681472f);
  return __builtin_fmaf(-2.0f, __builtin_amdgcn_rcpf(e + 1.0f), 1.0f);
}
__device__ __forceinline__ float neigh(float v){
  return __builtin_bit_cast(float,
      __builtin_amdgcn_mov_dpp(__builtin_bit_cast(int, v), 0xB1, 0xF, 0xF, true));
}
__device__ __forceinline__ uint32_t axor(uint32_t b){ return b ^ (((b>>7)&7u)<<4); }

// ---------------- sigma ----------------
__global__ void sigma_kernel(const float* __restrict__ lw, const float* __restrict__ lu,
                             const float* __restrict__ ow, const float* __restrict__ ou,
                             float* __restrict__ invs)
{
  __shared__ float sv[HID];
  __shared__ float red[8];
  const int g = threadIdx.x;
  const int m = blockIdx.x;
  const float* W = (m < 3) ? (lw + (size_t)m*HID*HID) : ow;
  const float* u = (m < 3) ? (lu + m*HID) : ou;
  float t1 = 0.f;
  for (int k = 0; k < HID; ++k) t1 += W[(size_t)k*HID + g] * u[k];
  float ss = t1*t1;
  #pragma unroll
  for (int d = 32; d; d >>= 1) ss += __shfl_xor(ss, d);
  if ((g & 63) == 0) red[g >> 6] = ss;
  __syncthreads();
  float tot = 0.f;
  #pragma unroll
  for (int i = 0; i < 8; ++i) tot += red[i];
  float nrm = sqrtf(tot);
  sv[g] = t1 / (nrm + 1e-12f);
  __syncthreads();
  float n = 0.f;
  const float* Wr = W + (size_t)g*HID;
  for (int k = 0; k < HID; ++k) n += Wr[k] * sv[k];
  float ss2 = n*n;
  #pragma unroll
  for (int d = 32; d; d >>= 1) ss2 += __shfl_xor(ss2, d);
  if ((g & 63) == 0) red[g >> 6] = ss2;
  __syncthreads();
  float tot2 = 0.f;
  #pragma unroll
  for (int i = 0; i < 8; ++i) tot2 += red[i];
  float nn = sqrtf(tot2);
  float sigma = tot2 / (nn + 1e-12f);
  if (g == 0) invs[m] = 1.0f / sigma;
}

// ---------------- weight packing: SINGLE fp16, frag-sequential 1 KiB frags ----------------
// Frag f = kt*NCT + ctg: element (lane*8 + j); lane l holds
// B[k = kt*32 + (l>>4)*8 + j][col = ctg*16 + (l&15)].
__global__ void pack_wsum_f16(const float* __restrict__ lw, const float* __restrict__ invs,
                              short* __restrict__ pw)
{
  int i = blockIdx.x*blockDim.x + threadIdx.x;   // < 512*512
  int j = i & 7, lane = (i >> 3) & 63, f = i >> 9;
  int kt = f >> 5, ctg = f & 31;                 // NCT = 32
  int k = kt*32 + (lane >> 4)*8 + j;
  int g = ctg*16 + (lane & 15);
  size_t idx = (size_t)g*HID + k;
  float v = lw[idx]*invs[0] + lw[262144 + idx]*invs[1] + lw[524288 + idx]*invs[2];
  pw[i] = f2h(v);
}

template<int K, int N>
__global__ void pack_b_f16(const float* __restrict__ W, short* __restrict__ pb)
{
  int i = blockIdx.x*blockDim.x + threadIdx.x;   // < K*N
  int j = i & 7, lane = (i >> 3) & 63, f = i >> 9;
  constexpr int NCT = N/16;
  int kt = f / NCT, ctg = f % NCT;
  int k = kt*32 + (lane >> 4)*8 + j;
  int c = ctg*16 + (lane & 15);
  pb[i] = f2h(W[(size_t)c*K + k]);
}

__global__ void pack_small(const float* __restrict__ lb, const float* __restrict__ ow,
                           const float* __restrict__ invs,
                           float* __restrict__ bsum, float* __restrict__ cs, float* __restrict__ cn)
{
  int g = blockIdx.x*blockDim.x + threadIdx.x;
  if (g >= HID) return;
  bsum[g] = lb[g] + lb[HID + g] + lb[2*HID + g];
  float is = invs[3];
  cs[g] = ow[(size_t)g*HID + g] * is;
  cn[g] = ow[(size_t)g*HID + (g^1)] * is;
}

// ---------------- fused main: 32 rows, 512 threads (8 waves), wave tile 32x64 ----------------
// R14 exactly (best measured: 1578 us). Single-pass fp16 recurrence (t and W
// both fp16); x_emb and head 2-pass. Two barriers/step keep all 8 waves
// phase-locked through the shared packW stream (L1/L2 line coalescing) —
// R17/R18/R19 proved every relaxation of this structure regresses.
__global__ void __launch_bounds__(512) fused_main(
    const float* __restrict__ x,
    const float* __restrict__ winb,
    const float* __restrict__ headb,
    const int*  __restrict__ stepsp,
    const short* __restrict__ packW,    // Wsum fp16, 512 KiB
    const short* __restrict__ packI,    // W_in fp16, 256 KiB
    const short* __restrict__ packHd,   // head fp16, 256 KiB
    const float* __restrict__ bsumA,
    const float* __restrict__ csA,
    const float* __restrict__ cnA,
    float* __restrict__ out)
{
  __shared__ char ldsbuf[65536];
  char* ldsHi = ldsbuf;             // 32 KiB A_hi (frag-major, 32 frags x 1 KiB)
  char* ldsLo = ldsbuf + 32768;     // 32 KiB A_lo (x_emb + head phases only)
  const int tid  = threadIdx.x;
  const int lane = tid & 63;
  const int l15  = lane & 15;
  const int ql   = lane >> 4;
  const int wc   = tid >> 6;        // 0..7, col group of 64
  const int rb   = blockIdx.x;

  const uint32_t laneRd = (uint32_t)((lane*16) ^ (((lane>>3)&7)<<4));

  // ---- stage x tile -> LDS fp16 hi/lo, frag-major [rtg 0..1][kt 0..7] ----
  {
    const float* xb = x + (size_t)rb*BROWS*IND;
    #pragma unroll
    for (int i = 0; i < 4; ++i) {
      int fi  = i*512 + tid;        // 2048 float4s
      int row = fi >> 6;
      int c   = (fi & 63)*4;
      f32x4 v = *(const f32x4*)(xb + (size_t)row*IND + c);
      short4v hi4, lo4;
      #pragma unroll
      for (int j = 0; j < 4; ++j) {
        short hh = f2h(v[j]);
        hi4[j] = hh;
        lo4[j] = f2h(v[j] - h2f(hh));
      }
      int rtg = row >> 4, kt = c >> 5, qd = (c >> 3) & 3;
      uint32_t byte = (uint32_t)(((rtg*8 + kt)*1024) + (qd*16 + (row & 15))*16 + (c & 7)*2);
      *(short4v*)(ldsHi + axor(byte)) = hi4;
      *(short4v*)(ldsLo + axor(byte)) = lo4;
    }
  }
  __syncthreads();

  const int nsteps = stepsp[0];

  const float cs_s = csA[wc*64 + l15];
  const float cn_s = cnA[wc*64 + l15];

  // ---- x_emb: single merged loop, acc[2][4], fp16 2-pass (exact A) ----
  f32x4 h[2][4];
  i32x4 xp[2][4];
  {
    f32x4 acc[2][4];
    #pragma unroll
    for (int ct = 0; ct < 4; ++ct) {
      int c = wc*64 + ct*16 + l15;
      float s = winb[c] + bsumA[c];
      #pragma unroll
      for (int rt = 0; rt < 2; ++rt) {
        f32x4 z; z[0]=s; z[1]=s; z[2]=s; z[3]=s;
        acc[rt][ct] = z;
      }
    }
    {
      const char* pI = (const char*)packI + (size_t)wc*4096 + (size_t)lane*16;
      __builtin_amdgcn_s_setprio(1);
      #pragma unroll 2
      for (int kt = 0; kt < 8; ++kt) {
        half8 b0 = *(const half8*)(pI);
        half8 b1 = *(const half8*)(pI + 1024);
        half8 b2 = *(const half8*)(pI + 2048);
        half8 b3 = *(const half8*)(pI + 3072);
        #pragma unroll
        for (int rt = 0; rt < 2; ++rt) {
          half8 ah = *(const half8*)(ldsHi + laneRd + (rt*8 + kt)*1024);
          half8 al = *(const half8*)(ldsLo + laneRd + (rt*8 + kt)*1024);
          acc[rt][0] = MFMAH(ah, b0, acc[rt][0]);
          acc[rt][0] = MFMAH(al, b0, acc[rt][0]);
          acc[rt][1] = MFMAH(ah, b1, acc[rt][1]);
          acc[rt][1] = MFMAH(al, b1, acc[rt][1]);
          acc[rt][2] = MFMAH(ah, b2, acc[rt][2]);
          acc[rt][2] = MFMAH(al, b2, acc[rt][2]);
          acc[rt][3] = MFMAH(ah, b3, acc[rt][3]);
          acc[rt][3] = MFMAH(al, b3, acc[rt][3]);
        }
        pI += 32768;
      }
      __builtin_amdgcn_s_setprio(0);
    }
    #pragma unroll
    for (int rt = 0; rt < 2; ++rt)
      #pragma unroll
      for (int ct = 0; ct < 4; ++ct)
        #pragma unroll
        for (int r = 0; r < 4; ++r) {
          float xv = acc[rt][ct][r];
          xp[rt][ct][r] = pack_hl(xv);
          h[rt][ct][r] = (nsteps >= 1) ? 0.5f * tanh_fast(xv) : 0.f;
        }
  }
  __syncthreads();

  const char* baseW = (const char*)packW + (size_t)wc*4096 + (size_t)lane*16;

  // ---- recurrence steps 2..nsteps (single-pass fp16) ----
  for (int s = 1; s < nsteps; ++s) {
    // t = tanh(h) -> LDS hi-plane fp16 A-tiles (frag (rt*16 + kt))
    #pragma unroll
    for (int rt = 0; rt < 2; ++rt) {
      uint32_t rcomp = (uint32_t)(rt*16384);
      #pragma unroll
      for (int ct = 0; ct < 4; ++ct) {
        int c = wc*64 + ct*16 + l15;
        uint32_t wcomp = (uint32_t)(((c >> 5)*1024) + (((c >> 3) & 3)*256) + ((c & 7)*2) + ql*64);
        #pragma unroll
        for (int r = 0; r < 4; ++r) {
          float t = tanh_fast(h[rt][ct][r]);
          uint32_t byte = axor(rcomp + wcomp + (uint32_t)(r*16));
          *(short*)(ldsHi + byte) = f2h(t);
        }
      }
    }
    __syncthreads();

    f32x4 acc[2][4];
    #pragma unroll
    for (int rt = 0; rt < 2; ++rt)
      #pragma unroll
      for (int ct = 0; ct < 4; ++ct)
        #pragma unroll
        for (int r = 0; r < 4; ++r) {
          float hv = h[rt][ct][r];
          acc[rt][ct][r] = __builtin_fmaf(cs_s, hv,
                             __builtin_fmaf(cn_s, neigh(hv), unpk(xp[rt][ct][r])));
        }
    {
      const char* p = baseW;
      __builtin_amdgcn_s_setprio(1);
      #pragma unroll 4
      for (int kt = 0; kt < 16; ++kt) {
        half8 b0 = *(const half8*)(p);
        half8 b1 = *(const half8*)(p + 1024);
        half8 b2 = *(const half8*)(p + 2048);
        half8 b3 = *(const half8*)(p + 3072);
        #pragma unroll
        for (int rt = 0; rt < 2; ++rt) {
          half8 ah = *(const half8*)(ldsHi + laneRd + (rt*16 + kt)*1024);
          acc[rt][0] = MFMAH(ah, b0, acc[rt][0]);
          acc[rt][1] = MFMAH(ah, b1, acc[rt][1]);
          acc[rt][2] = MFMAH(ah, b2, acc[rt][2]);
          acc[rt][3] = MFMAH(ah, b3, acc[rt][3]);
        }
        p += 32768;
      }
      __builtin_amdgcn_s_setprio(0);
    }
    #pragma unroll
    for (int rt = 0; rt < 2; ++rt)
      #pragma unroll
      for (int ct = 0; ct < 4; ++ct)
        #pragma unroll
        for (int r = 0; r < 4; ++r)
          h[rt][ct][r] = __builtin_fmaf(0.5f, tanh_fast(acc[rt][ct][r]), 0.5f*h[rt][ct][r]);
    __syncthreads();
  }

  // ---- head: out = h @ head_w^T + head_b (h split hi/lo fp16, W single fp16) ----
  #pragma unroll
  for (int rt = 0; rt < 2; ++rt) {
    uint32_t rcomp = (uint32_t)(rt*16384);
    #pragma unroll
    for (int ct = 0; ct < 4; ++ct) {
      int c = wc*64 + ct*16 + l15;
      uint32_t wcomp = (uint32_t)(((c >> 5)*1024) + (((c >> 3) & 3)*256) + ((c & 7)*2) + ql*64);
      #pragma unroll
      for (int r = 0; r < 4; ++r) {
        float hv = h[rt][ct][r];
        short hh = f2h(hv);
        uint32_t byte = axor(rcomp + wcomp + (uint32_t)(r*16));
        *(short*)(ldsHi + byte) = hh;
        *(short*)(ldsLo + byte) = f2h(hv - h2f(hh));
      }
    }
  }
  __syncthreads();

  int oc[2]; float hbv[2];
  #pragma unroll
  for (int c2 = 0; c2 < 2; ++c2) { oc[c2] = wc*32 + c2*16 + l15; hbv[c2] = headb[oc[c2]]; }
  f32x4 o[2][2];
  #pragma unroll
  for (int rt = 0; rt < 2; ++rt)
    #pragma unroll
    for (int c2 = 0; c2 < 2; ++c2) {
      f32x4 z; z[0]=hbv[c2]; z[1]=hbv[c2]; z[2]=hbv[c2]; z[3]=hbv[c2];
      o[rt][c2] = z;
    }
  {
    const char* pHd = (const char*)packHd + (size_t)wc*2048 + (size_t)lane*16;
    #pragma unroll 2
    for (int kt = 0; kt < 16; ++kt) {
      #pragma unroll
      for (int rt = 0; rt < 2; ++rt) {
        half8 ah = *(const half8*)(ldsHi + laneRd + (rt*16 + kt)*1024);
        half8 al = *(const half8*)(ldsLo + laneRd + (rt*16 + kt)*1024);
        #pragma unroll
        for (int c2 = 0; c2 < 2; ++c2) {
          half8 b = *(const half8*)(pHd + c2*1024);
          o[rt][c2] = MFMAH(ah, b, o[rt][c2]);
          o[rt][c2] = MFMAH(al, b, o[rt][c2]);
        }
      }
      pHd += 16384;
    }
  }
  const size_t rowg = (size_t)rb*BROWS;
  #pragma unroll
  for (int rt = 0; rt < 2; ++rt)
    #pragma unroll
    for (int c2 = 0; c2 < 2; ++c2)
      #pragma unroll
      for (int r = 0; r < 4; ++r) {
        size_t row = rowg + rt*16 + ql*4 + r;
        out[row*OUTD + oc[c2]] = o[rt][c2][r];
      }
}

extern "C" void kernel_launch(void* const* d_in, const int* in_sizes, int n_in,
                              void* d_out, int out_size, void* d_ws, size_t ws_size,
                              hipStream_t stream)
{
  const float* x    = (const float*)d_in[0];
  const float* winw = (const float*)d_in[1];
  const float* winb = (const float*)d_in[2];
  const float* lw   = (const float*)d_in[3];
  const float* lb   = (const float*)d_in[4];
  const float* lu   = (const float*)d_in[5];
  const float* ow   = (const float*)d_in[6];
  const float* ou   = (const float*)d_in[7];
  const float* hw   = (const float*)d_in[8];
  const float* hb   = (const float*)d_in[9];
  const int*   st   = (const int*)d_in[10];
  float* out = (float*)d_out;
  char*  ws  = (char*)d_ws;

  float* invs   = (float*)(ws);
  float* bsum   = (float*)(ws + 1024);
  float* cs     = (float*)(ws + 4096);
  float* cn     = (float*)(ws + 8192);
  short* packW  = (short*)(ws + 16384);                    // 512 KiB fp16
  short* packI  = (short*)(ws + 16384 + 524288);           // 256 KiB fp16
  short* packHd = (short*)(ws + 16384 + 524288 + 262144);  // 256 KiB fp16

  sigma_kernel<<<4, 512, 0, stream>>>(lw, lu, ow, ou, invs);
  pack_wsum_f16<<<1024, 256, 0, stream>>>(lw, invs, packW);
  pack_b_f16<256, 512><<<512, 256, 0, stream>>>(winw, packI);
  pack_b_f16<512, 256><<<512, 256, 0, stream>>>(hw, packHd);
  pack_small<<<2, 256, 0, stream>>>(lb, ow, invs, bsum, cs, cn);

  fused_main<<<65536/BROWS, 512, 0, stream>>>(x, winb, hb, st,
                                              packW, packI, packHd,
                                              bsum, cs, cn, out);
}